// Round 1
// baseline (117.007 us; speedup 1.0000x reference)
//
#include <hip/hip_runtime.h>
#include <hip/hip_bf16.h>

// Problem: N=8, L=S=1024, C=256, H=8, D=32
// out = (v1 * softmax_S(q k^T / sqrt(D)) v2) @ Wp^T + bp
// Pipeline: prep (add+bf16) -> 4 projections (MFMA GEMM) -> fused attn -> out GEMM

typedef __bf16 bf16_t;
using bf16x8 = __attribute__((ext_vector_type(8))) __bf16;
using f32x4  = __attribute__((ext_vector_type(4))) float;

#define NB 8
#define LL 1024
#define SS 1024
#define CC 256
#define HH 8
#define DD 32
#define MTOK (NB * LL)   // 8192 tokens for both L-side and S-side

static __device__ __forceinline__ f32x4 mfma16(bf16x8 a, bf16x8 b, f32x4 c) {
  return __builtin_amdgcn_mfma_f32_16x16x32_bf16(a, b, c, 0, 0, 0);
}

// ---------------------------------------------------------------------------
// Kernel 1: xq = bf16(x + xe), sk = bf16(s1 + se), plus bf16 copies of weights
// ---------------------------------------------------------------------------
__global__ __launch_bounds__(256) void prep_kernel(
    const float* __restrict__ x, const float* __restrict__ xe,
    const float* __restrict__ s1, const float* __restrict__ se,
    const float* __restrict__ wq, const float* __restrict__ wk,
    const float* __restrict__ wv, const float* __restrict__ wp,
    bf16_t* __restrict__ XQ, bf16_t* __restrict__ SK, bf16_t* __restrict__ Wall) {
  const int TOK4 = (MTOK * CC) / 4;  // 524288 float4 per token tensor
  const int W4   = (CC * CC) / 4;    // 16384 float4 per weight matrix
  int i = blockIdx.x * 256 + threadIdx.x;
  const int stride = gridDim.x * 256;
  const int total = 2 * TOK4 + 4 * W4;
  for (; i < total; i += stride) {
    const float4* pa;
    const float4* pb = nullptr;
    bf16_t* o;
    int j;
    if (i < TOK4) {
      pa = (const float4*)x; pb = (const float4*)xe; o = XQ; j = i;
    } else if (i < 2 * TOK4) {
      pa = (const float4*)s1; pb = (const float4*)se; o = SK; j = i - TOK4;
    } else {
      int wi = i - 2 * TOK4;
      int w = wi >> 14;          // / W4
      j = wi & (W4 - 1);
      pa = (const float4*)(w == 0 ? wq : w == 1 ? wk : w == 2 ? wv : wp);
      o = Wall + (size_t)w * CC * CC;
    }
    float4 va = pa[j];
    if (pb) {
      float4 vb = pb[j];
      va.x += vb.x; va.y += vb.y; va.z += vb.z; va.w += vb.w;
    }
    bf16_t t4[4] __attribute__((aligned(8))) = {
        (bf16_t)va.x, (bf16_t)va.y, (bf16_t)va.z, (bf16_t)va.w};
    *(uint2*)(o + 4 * (size_t)j) = *(const uint2*)t4;
  }
}

// ---------------------------------------------------------------------------
// Kernel 2: projections.  out[m][n] = sum_k A[m][k] * W[n][k]   (NT GEMM)
// z=0: Q = XQ*Wq  (row-major bf16 [8192][256])
// z=1: K = SK*Wk  (row-major bf16)
// z=2: V1 = XQ*Wv (row-major bf16)
// z=3: V2T = SK*Wv stored transposed per head: [n][h][d][s] bf16
// Fragment mapping (mfma_f32_16x16x32_bf16):
//   A: lane holds A[lane&15][(lane>>4)*8 + j]   (16B contiguous along K)
//   B: lane holds B[(lane>>4)*8 + j][lane&15] = W[lane&15][(lane>>4)*8+j]
//   C/D: col = lane&15, row = (lane>>4)*4 + reg   [m89-verified]
// ---------------------------------------------------------------------------
__global__ __launch_bounds__(256) void proj_kernel(
    const bf16_t* __restrict__ XQ, const bf16_t* __restrict__ SK,
    const bf16_t* __restrict__ Wall,
    bf16_t* __restrict__ Qw, bf16_t* __restrict__ Kw,
    bf16_t* __restrict__ V1w, bf16_t* __restrict__ V2T) {
  const int lane = threadIdx.x & 63;
  const int wid = threadIdx.x >> 6;
  const int wm = wid >> 1, wn = wid & 1;
  const int r = lane & 15, g = lane >> 4;
  const int bm = blockIdx.x * 64, bn = blockIdx.y * 64;
  const int z = blockIdx.z;

  const bf16_t* A = (z == 1 || z == 3) ? SK : XQ;
  const bf16_t* W = Wall + (size_t)(z == 0 ? 0 : z == 1 ? 1 : 2) * CC * CC;

  const int row_a0 = bm + wm * 32;
  const int col_b0 = bn + wn * 32;

  f32x4 acc[2][2] = {};
#pragma unroll
  for (int k0 = 0; k0 < CC; k0 += 32) {
    bf16x8 a0 = *(const bf16x8*)(A + (size_t)(row_a0 + r) * CC + k0 + g * 8);
    bf16x8 a1 = *(const bf16x8*)(A + (size_t)(row_a0 + 16 + r) * CC + k0 + g * 8);
    bf16x8 b0 = *(const bf16x8*)(W + (size_t)(col_b0 + r) * CC + k0 + g * 8);
    bf16x8 b1 = *(const bf16x8*)(W + (size_t)(col_b0 + 16 + r) * CC + k0 + g * 8);
    acc[0][0] = mfma16(a0, b0, acc[0][0]);
    acc[0][1] = mfma16(a0, b1, acc[0][1]);
    acc[1][0] = mfma16(a1, b0, acc[1][0]);
    acc[1][1] = mfma16(a1, b1, acc[1][1]);
  }

  bf16_t* O = (z == 0) ? Qw : (z == 1) ? Kw : V1w;
#pragma unroll
  for (int i = 0; i < 2; ++i) {
#pragma unroll
    for (int j = 0; j < 2; ++j) {
      const int row_base = row_a0 + i * 16 + g * 4;
      const int col = col_b0 + j * 16 + r;
      if (z < 3) {
#pragma unroll
        for (int t = 0; t < 4; ++t)
          O[(size_t)(row_base + t) * CC + col] = (bf16_t)acc[i][j][t];
      } else {
        // transposed per-head store: V2T[((n*H + h)*D + d)][s], s = row&1023
        const int n = row_base >> 10;
        const int s = row_base & (SS - 1);
        const int h = col >> 5;
        const int d = col & (DD - 1);
        bf16_t t4[4] __attribute__((aligned(8)));
#pragma unroll
        for (int t = 0; t < 4; ++t) t4[t] = (bf16_t)acc[i][j][t];
        *(uint2*)(V2T + ((size_t)((n * HH + h) * DD + d)) * SS + s) =
            *(const uint2*)t4;
      }
    }
  }
}

// ---------------------------------------------------------------------------
// Kernel 3: fused flash attention + v1 gating.
// Grid (L/64, H, N), 4 waves/WG, each wave owns 16 L-rows.
// Swapped QK^T: P^T = mfma(K_frag, Q_frag): lane col (lane&15) = L, rows = S.
// Online softmax over S (within-lane over 8 regs + shfl_xor 16/32).
// P staged per-wave in LDS -> A-fragment for PV. V2 read from V2T (contig).
// ---------------------------------------------------------------------------
__global__ __launch_bounds__(256) void attn_kernel(
    const bf16_t* __restrict__ Qw, const bf16_t* __restrict__ Kw,
    const bf16_t* __restrict__ V1w, const bf16_t* __restrict__ V2T,
    bf16_t* __restrict__ MSG) {
  __shared__ bf16_t p_lds[4][16][40];  // per-wave 16x32 P tile, pad to 40

  const int lane = threadIdx.x & 63;
  const int wid = threadIdx.x >> 6;
  const int r = lane & 15, g = lane >> 4;
  const int lt = blockIdx.x;   // L-tile of 64
  const int h = blockIdx.y;
  const int n = blockIdx.z;
  const int lrow0 = lt * 64 + wid * 16;
  const size_t tokQ = (size_t)n * LL + lrow0;

  // Q fragment (B-operand of swapped QK^T), loaded once
  const bf16x8 qf = *(const bf16x8*)(Qw + (tokQ + r) * CC + h * DD + g * 8);
  const bf16_t* Kb = Kw + ((size_t)n * SS) * CC + h * DD;
  const bf16_t* Vt = V2T + ((size_t)(n * HH + h)) * DD * SS;

  float m_run = -1e30f;
  float l_run = 0.f;
  f32x4 o0 = {0.f, 0.f, 0.f, 0.f};
  f32x4 o1 = {0.f, 0.f, 0.f, 0.f};
  const f32x4 zero = {0.f, 0.f, 0.f, 0.f};
  // 1/sqrt(32) * log2(e): do softmax in exp2 space
  const float cscale = 0.17677669529663688f * 1.4426950408889634f;

  for (int s0 = 0; s0 < SS; s0 += 32) {
    bf16x8 kf0 = *(const bf16x8*)(Kb + (size_t)(s0 + r) * CC + g * 8);
    bf16x8 kf1 = *(const bf16x8*)(Kb + (size_t)(s0 + 16 + r) * CC + g * 8);
    f32x4 pt0 = mfma16(kf0, qf, zero);  // rows = s0+g*4+reg, col = L (lane&15)
    f32x4 pt1 = mfma16(kf1, qf, zero);  // rows = s0+16+g*4+reg

    float t[8];
#pragma unroll
    for (int i = 0; i < 4; ++i) {
      t[i] = pt0[i] * cscale;
      t[4 + i] = pt1[i] * cscale;
    }
    float mx = t[0];
#pragma unroll
    for (int i = 1; i < 8; ++i) mx = fmaxf(mx, t[i]);
    mx = fmaxf(mx, __shfl_xor(mx, 16));
    mx = fmaxf(mx, __shfl_xor(mx, 32));
    const float m_new = fmaxf(m_run, mx);
    const float fac = exp2f(m_run - m_new);

    float p[8];
    float psum = 0.f;
#pragma unroll
    for (int i = 0; i < 8; ++i) {
      p[i] = exp2f(t[i] - m_new);
      psum += p[i];
    }
    psum += __shfl_xor(psum, 16);
    psum += __shfl_xor(psum, 32);
    l_run = l_run * fac + psum;
    m_run = m_new;

    // stage P (bf16) into LDS in [L][s] layout for the PV A-fragment
    bf16_t pb[8] __attribute__((aligned(8)));
#pragma unroll
    for (int i = 0; i < 8; ++i) pb[i] = (bf16_t)p[i];
    *(uint2*)&p_lds[wid][r][g * 4] = *(const uint2*)&pb[0];
    *(uint2*)&p_lds[wid][r][16 + g * 4] = *(const uint2*)&pb[4];

    // rescale O accumulators (per L-row factor lives in lane (row&15))
    float fr[4];
#pragma unroll
    for (int i = 0; i < 4; ++i) fr[i] = __shfl(fac, g * 4 + i);
#pragma unroll
    for (int i = 0; i < 4; ++i) {
      o0[i] *= fr[i];
      o1[i] *= fr[i];
    }

    // PV: O[l][d] += P[l][s] * V2[s][d]
    bf16x8 pf = *(const bf16x8*)&p_lds[wid][r][g * 8];
    bf16x8 v2a = *(const bf16x8*)(Vt + (size_t)r * SS + s0 + g * 8);
    bf16x8 v2b = *(const bf16x8*)(Vt + (size_t)(16 + r) * SS + s0 + g * 8);
    o0 = mfma16(pf, v2a, o0);  // d cols 0..15
    o1 = mfma16(pf, v2b, o1);  // d cols 16..31
  }

  const float linv = 1.f / l_run;
  float li[4];
#pragma unroll
  for (int i = 0; i < 4; ++i) li[i] = __shfl(linv, g * 4 + i);

  const bf16_t* V1b = V1w + tokQ * CC + h * DD;
  bf16_t* Mb = MSG + tokQ * CC + h * DD;
#pragma unroll
  for (int i = 0; i < 4; ++i) {
    const size_t ro = (size_t)(g * 4 + i) * CC;
    const float va = (float)V1b[ro + r];
    const float vb = (float)V1b[ro + 16 + r];
    Mb[ro + r] = (bf16_t)(va * o0[i] * li[i]);
    Mb[ro + 16 + r] = (bf16_t)(vb * o1[i] * li[i]);
  }
}

// ---------------------------------------------------------------------------
// Kernel 4: out = MSG @ Wp^T + bp   (f32 output)
// ---------------------------------------------------------------------------
__global__ __launch_bounds__(256) void out_kernel(
    const bf16_t* __restrict__ MSG, const bf16_t* __restrict__ Wp,
    const float* __restrict__ bp, float* __restrict__ out) {
  const int lane = threadIdx.x & 63;
  const int wid = threadIdx.x >> 6;
  const int wm = wid >> 1, wn = wid & 1;
  const int r = lane & 15, g = lane >> 4;
  const int bm = blockIdx.x * 64, bn = blockIdx.y * 64;
  const int row_a0 = bm + wm * 32;
  const int col_b0 = bn + wn * 32;

  f32x4 acc[2][2] = {};
#pragma unroll
  for (int k0 = 0; k0 < CC; k0 += 32) {
    bf16x8 a0 = *(const bf16x8*)(MSG + (size_t)(row_a0 + r) * CC + k0 + g * 8);
    bf16x8 a1 = *(const bf16x8*)(MSG + (size_t)(row_a0 + 16 + r) * CC + k0 + g * 8);
    bf16x8 b0 = *(const bf16x8*)(Wp + (size_t)(col_b0 + r) * CC + k0 + g * 8);
    bf16x8 b1 = *(const bf16x8*)(Wp + (size_t)(col_b0 + 16 + r) * CC + k0 + g * 8);
    acc[0][0] = mfma16(a0, b0, acc[0][0]);
    acc[0][1] = mfma16(a0, b1, acc[0][1]);
    acc[1][0] = mfma16(a1, b0, acc[1][0]);
    acc[1][1] = mfma16(a1, b1, acc[1][1]);
  }
#pragma unroll
  for (int i = 0; i < 2; ++i) {
#pragma unroll
    for (int j = 0; j < 2; ++j) {
      const int row_base = row_a0 + i * 16 + g * 4;
      const int col = col_b0 + j * 16 + r;
      const float bv = bp[col];
#pragma unroll
      for (int t = 0; t < 4; ++t)
        out[(size_t)(row_base + t) * CC + col] = acc[i][j][t] + bv;
    }
  }
}

// ---------------------------------------------------------------------------
extern "C" void kernel_launch(void* const* d_in, const int* in_sizes, int n_in,
                              void* d_out, int out_size, void* d_ws,
                              size_t ws_size, hipStream_t stream) {
  const float* x  = (const float*)d_in[0];
  const float* s1 = (const float*)d_in[1];
  const float* xe = (const float*)d_in[2];
  const float* se = (const float*)d_in[3];
  const float* Wq = (const float*)d_in[4];
  const float* Wk = (const float*)d_in[5];
  const float* Wv = (const float*)d_in[6];
  const float* Wp = (const float*)d_in[7];
  const float* bp = (const float*)d_in[8];
  float* out = (float*)d_out;

  char* ws = (char*)d_ws;
  // workspace layout (29 MB total)
  bf16_t* XQ   = (bf16_t*)(ws);                     // 4 MB  [8192][256]
  bf16_t* SK   = (bf16_t*)(ws + (4u << 20));        // 4 MB
  bf16_t* Wall = (bf16_t*)(ws + (8u << 20));        // 512 KB: Wq,Wk,Wv,Wp bf16
  bf16_t* Qw   = (bf16_t*)(ws + (9u << 20));        // 4 MB
  bf16_t* Kw   = (bf16_t*)(ws + (13u << 20));       // 4 MB
  bf16_t* V1w  = (bf16_t*)(ws + (17u << 20));       // 4 MB
  bf16_t* V2T  = (bf16_t*)(ws + (21u << 20));       // 4 MB [n][h][d][s]
  bf16_t* MSG  = (bf16_t*)(ws + (25u << 20));       // 4 MB
  bf16_t* Wpb  = Wall + 3 * CC * CC;

  prep_kernel<<<2048, 256, 0, stream>>>(x, xe, s1, se, Wq, Wk, Wv, Wp, XQ, SK,
                                        Wall);
  proj_kernel<<<dim3(MTOK / 64, CC / 64, 4), 256, 0, stream>>>(
      XQ, SK, Wall, Qw, Kw, V1w, V2T);
  attn_kernel<<<dim3(LL / 64, HH, NB), 256, 0, stream>>>(Qw, Kw, V1w, V2T, MSG);
  out_kernel<<<dim3(MTOK / 64, CC / 64, 1), 256, 0, stream>>>(MSG, Wpb, bp, out);
}